// Round 2
// baseline (94.480 us; speedup 1.0000x reference)
//
#include <hip/hip_runtime.h>

#define D8      8
#define LPATH   2048
#define NBATCH  64
#define NSTEPS  2047         // L-1 increments
#define NCHUNK  32
#define CSTEPS  64           // increments per chunk (last chunk: 63)
#define SIGLEN  4680         // 8 + 64 + 512 + 4096
#define SIGPAD  4688         // +8 for swizzle overflow
#define OFF2    8
#define OFF3    72
#define OFF4    584

__device__ __forceinline__ void load8(const float* __restrict__ p, float* v) {
    float4 a = ((const float4*)p)[0];
    float4 b = ((const float4*)p)[1];
    v[0]=a.x; v[1]=a.y; v[2]=a.z; v[3]=a.w;
    v[4]=b.x; v[5]=b.y; v[6]=b.z; v[7]=b.w;
}
__device__ __forceinline__ void store8(float* __restrict__ p, const float* v) {
    ((float4*)p)[0] = make_float4(v[0],v[1],v[2],v[3]);
    ((float4*)p)[1] = make_float4(v[4],v[5],v[6],v[7]);
}

// ============================ Phase 1 ============================
// 2 waves per chunk; wave w owns k in [KB, KB+4) of A3/A4. A2/a1i redundant.

__device__ __forceinline__ void load_pt(const float* __restrict__ pb, int t, int i, int j,
                                        float (&P)[8], float& Pi, float& Pj) {
    load8(pb + (size_t)t * D8, P);
    Pi = pb[t * D8 + i];
    Pj = pb[t * D8 + j];
}

template<int KB>
__device__ __forceinline__ void sig_step(const float (&C)[8], float Ci, float Cj,
                                         const float (&N)[8], float Ni, float Nj,
                                         float (&A4)[4][8], float (&A3)[4],
                                         float& A2, float& a1i) {
    float z[8];
#pragma unroll
    for (int m = 0; m < 8; ++m) z[m] = N[m] - C[m];
    const float zi = Ni - Ci, zj = Nj - Cj;
    const float p  = zi * zj;
    const float uq = a1i * zj;
    const float c4 = fmaf(uq, 1.f/6.f, fmaf(p, 1.f/24.f, A2 * 0.5f));
    const float c3 = fmaf(uq, 0.5f,    fmaf(p, 1.f/6.f,  A2));
#pragma unroll
    for (int kk = 0; kk < 4; ++kk) {
        const float zk = z[KB + kk];                 // compile-time index
        const float f  = fmaf(c4, zk, A3[kk]);
#pragma unroll
        for (int l = 0; l < 8; ++l) A4[kk][l] = fmaf(f, z[l], A4[kk][l]);
        A3[kk] = fmaf(c3, zk, A3[kk]);
    }
    A2 = A2 + fmaf(p, 0.5f, uq);
    a1i += zi;
}

template<int KB>
__device__ __forceinline__ void chunk_body(const float* __restrict__ pb,
                                           float* __restrict__ o,
                                           int t0, int t1, int lane, int i, int j) {
    float A4[4][8], A3[4];
    float A2 = 0.f, a1i = 0.f;
#pragma unroll
    for (int kk = 0; kk < 4; ++kk) {
        A3[kk] = 0.f;
#pragma unroll
        for (int l = 0; l < 8; ++l) A4[kk][l] = 0.f;
    }

    float P0[8], P1[8], P2[8];
    float P0i, P0j, P1i, P1j, P2i, P2j;
    load_pt(pb, t0,     i, j, P0, P0i, P0j);
    load_pt(pb, t0 + 1, i, j, P1, P1i, P1j);
    {
        const int tc = (t0 + 2 > t1) ? t1 : t0 + 2;
        load_pt(pb, tc, i, j, P2, P2i, P2j);
    }

    const int n = t1 - t0;          // 64 or 63
    const int triples = n / 3;
    int t = t0;
    for (int r = 0; r < triples; ++r) {
        sig_step<KB>(P0, P0i, P0j, P1, P1i, P1j, A4, A3, A2, a1i);
        { const int ta = (t + 3 > t1) ? t1 : t + 3; load_pt(pb, ta, i, j, P0, P0i, P0j); }
        sig_step<KB>(P1, P1i, P1j, P2, P2i, P2j, A4, A3, A2, a1i);
        { const int tb = (t + 4 > t1) ? t1 : t + 4; load_pt(pb, tb, i, j, P1, P1i, P1j); }
        sig_step<KB>(P2, P2i, P2j, P0, P0i, P0j, A4, A3, A2, a1i);
        { const int tc = (t + 5 > t1) ? t1 : t + 5; load_pt(pb, tc, i, j, P2, P2i, P2j); }
        t += 3;
    }
    const int rem = n - triples * 3;  // 0 or 1
    if (rem >= 1) sig_step<KB>(P0, P0i, P0j, P1, P1i, P1j, A4, A3, A2, a1i);
    if (rem >= 2) sig_step<KB>(P1, P1i, P1j, P2, P2i, P2j, A4, A3, A2, a1i);

    if (KB == 0) {
        if (lane < 8) o[lane] = pb[(size_t)t1 * D8 + lane] - pb[(size_t)t0 * D8 + lane];
        o[OFF2 + lane] = A2;
    }
    *(float4*)(o + OFF3 + lane * 8 + KB) = make_float4(A3[0], A3[1], A3[2], A3[3]);
#pragma unroll
    for (int kk = 0; kk < 4; ++kk)
        store8(o + OFF4 + lane * 64 + (KB + kk) * 8, A4[kk]);
}

__global__ __launch_bounds__(128, 4) void sig_chunk_kernel(const float* __restrict__ path,
                                                           float* __restrict__ sigs) {
    const int wg   = blockIdx.x;             // b*NCHUNK + c
    const int b    = wg >> 5;
    const int c    = wg & (NCHUNK - 1);
    const int w    = threadIdx.x >> 6;
    const int lane = threadIdx.x & 63;
    const int i    = lane >> 3;
    const int j    = lane & 7;
    const int t0   = c * CSTEPS;
    const int t1   = (t0 + CSTEPS < NSTEPS) ? (t0 + CSTEPS) : NSTEPS;
    const float* __restrict__ pb = path + (size_t)b * LPATH * D8;
    float* __restrict__ o = sigs + (size_t)wg * SIGLEN;
    if (w == 0) chunk_body<0>(pb, o, t0, t1, lane, i, j);
    else        chunk_body<4>(pb, o, t0, t1, lane, i, j);
}

// ============================ Phase 2 (fused tree) ============================
// 1 block per batch, 4 waves. Wave wv folds chunks [8wv,8wv+8); waves 1-3 park
// partials in swizzled LDS; wave 0 folds the 3 partials and writes out.

__device__ __forceinline__ int swz(int idx) {
    int g = idx >> 3;
    g ^= (g >> 3) & 3;
    return (g << 3) | (idx & 7);
}
template<bool S> __device__ __forceinline__ float ld1(const float* __restrict__ B, int idx) {
    return B[S ? swz(idx) : idx];
}
template<bool S> __device__ __forceinline__ void ld8(const float* __restrict__ B, int idx, float* v) {
    load8(B + (S ? swz(idx) : idx), v);
}

template<bool S>
__device__ __forceinline__ void combine_step(float (&A4)[8][8], float (&A3)[8], float (&A1)[8],
                                             float& A2, float& a1i,
                                             const float* __restrict__ B,
                                             int lane, int i, int j) {
    float B1[8];   ld8<S>(B, 0, B1);
    const float b1i = ld1<S>(B, i);
    const float b1j = ld1<S>(B, j);
    const float b2t = ld1<S>(B, OFF2 + lane);
    float b3ij[8]; ld8<S>(B, OFF3 + lane * 8, b3ij);   // B3[i,j,:]
    float b2j[8];  ld8<S>(B, OFF2 + j * 8, b2j);       // B2[j,:]

    // C4[i,j,k,l] = A4 + B4 + A3[k]*B1[l] + A2*B2[k,l] + A1[i]*B3[j,k,l]
#pragma unroll
    for (int k = 0; k < 8; ++k) {
        float b4r[8]; ld8<S>(B, OFF4 + lane * 64 + k * 8, b4r);
        float b2r[8]; ld8<S>(B, OFF2 + k * 8, b2r);
        float b3r[8]; ld8<S>(B, OFF3 + j * 64 + k * 8, b3r);
#pragma unroll
        for (int l = 0; l < 8; ++l) {
            float v = A4[k][l] + b4r[l];
            v = fmaf(A3[k], B1[l], v);
            v = fmaf(A2,    b2r[l], v);
            A4[k][l] = fmaf(a1i, b3r[l], v);
        }
    }
#pragma unroll
    for (int k = 0; k < 8; ++k) {
        float v = A3[k] + b3ij[k];
        v = fmaf(A2, B1[k], v);
        A3[k] = fmaf(a1i, b2j[k], v);
    }
    A2 = A2 + fmaf(a1i, b1j, b2t);
#pragma unroll
    for (int m = 0; m < 8; ++m) A1[m] += B1[m];
    a1i += b1i;
}

__global__ __launch_bounds__(256) void sig_combine_kernel(const float* __restrict__ sigs,
                                                          float* __restrict__ out) {
    __shared__ float lds[3][SIGPAD];
    const int b    = blockIdx.x;
    const int wv   = threadIdx.x >> 6;
    const int lane = threadIdx.x & 63;
    const int i    = lane >> 3;
    const int j    = lane & 7;
    const float* __restrict__ base = sigs + ((size_t)b * NCHUNK + (size_t)wv * 8) * SIGLEN;

    float A4[8][8], A3[8], A1[8], A2, a1i;
    load8(base, A1);
    a1i = base[i];
    A2  = base[OFF2 + lane];
    load8(base + OFF3 + lane * 8, A3);
#pragma unroll
    for (int k = 0; k < 8; ++k) load8(base + OFF4 + lane * 64 + k * 8, A4[k]);

    for (int s = 1; s < 8; ++s)
        combine_step<false>(A4, A3, A1, A2, a1i, base + (size_t)s * SIGLEN, lane, i, j);

    if (wv > 0) {
        float* L = lds[wv - 1];
        if (lane < 8) L[swz(lane)] = A1[lane];
        L[swz(OFF2 + lane)] = A2;
        store8(L + swz(OFF3 + lane * 8), A3);
#pragma unroll
        for (int k = 0; k < 8; ++k) store8(L + swz(OFF4 + lane * 64 + k * 8), A4[k]);
    }
    __syncthreads();

    if (wv == 0) {
        for (int s = 0; s < 3; ++s)
            combine_step<true>(A4, A3, A1, A2, a1i, lds[s], lane, i, j);
        float* __restrict__ o = out + (size_t)b * SIGLEN;
        if (lane < 8) o[lane] = A1[lane];
        o[OFF2 + lane] = A2;
        store8(o + OFF3 + lane * 8, A3);
#pragma unroll
        for (int k = 0; k < 8; ++k) store8(o + OFF4 + lane * 64 + k * 8, A4[k]);
    }
}

extern "C" void kernel_launch(void* const* d_in, const int* in_sizes, int n_in,
                              void* d_out, int out_size, void* d_ws, size_t ws_size,
                              hipStream_t stream) {
    const float* path = (const float*)d_in[0];
    float* out  = (float*)d_out;
    float* sigs = (float*)d_ws;                 // 64*32*4680 f32 = 38.3 MB

    sig_chunk_kernel<<<NBATCH * NCHUNK, 128, 0, stream>>>(path, sigs);
    sig_combine_kernel<<<NBATCH, 256, 0, stream>>>(sigs, out);
}

// Round 3
// 62.067 us; speedup vs baseline: 1.5222x; 1.5222x over previous
//
#include <hip/hip_runtime.h>

#define D8      8
#define LPATH   2048
#define NBATCH  64
#define NSTEPS  2047         // L-1 increments
#define NCHUNK  32
#define CSTEPS  64           // increments per chunk (last chunk: 63)
#define SIGLEN  4680         // 8 + 64 + 512 + 4096
#define OFF2    8
#define OFF3    72
#define OFF4    584

__device__ __forceinline__ void load8(const float* __restrict__ p, float* v) {
    float4 a = ((const float4*)p)[0];
    float4 b = ((const float4*)p)[1];
    v[0]=a.x; v[1]=a.y; v[2]=a.z; v[3]=a.w;
    v[4]=b.x; v[5]=b.y; v[6]=b.z; v[7]=b.w;
}
__device__ __forceinline__ void store8(float* __restrict__ p, const float* v) {
    ((float4*)p)[0] = make_float4(v[0],v[1],v[2],v[3]);
    ((float4*)p)[1] = make_float4(v[4],v[5],v[6],v[7]);
}

// ============================ Phase 1 ============================
// One block of 128 per chunk; wave w owns k in [4w, 4w+4) of A3/A4.

__device__ __forceinline__ void load_pt(const float* __restrict__ pb, int t, int i, int j,
                                        float (&P)[8], float& Pi, float& Pj) {
    load8(pb + (size_t)t * D8, P);
    Pi = pb[t * D8 + i];
    Pj = pb[t * D8 + j];
}

template<int KB>
__device__ __forceinline__ void sig_step(const float (&C)[8], float Ci, float Cj,
                                         const float (&N)[8], float Ni, float Nj,
                                         float (&A4)[4][8], float (&A3)[4],
                                         float& A2, float& a1i) {
    float z[8];
#pragma unroll
    for (int m = 0; m < 8; ++m) z[m] = N[m] - C[m];
    const float zi = Ni - Ci, zj = Nj - Cj;
    const float p  = zi * zj;
    const float uq = a1i * zj;
    const float c4 = fmaf(uq, 1.f/6.f, fmaf(p, 1.f/24.f, A2 * 0.5f));
    const float c3 = fmaf(uq, 0.5f,    fmaf(p, 1.f/6.f,  A2));
#pragma unroll
    for (int kk = 0; kk < 4; ++kk) {
        const float zk = z[KB + kk];                 // compile-time index
        const float f  = fmaf(c4, zk, A3[kk]);
#pragma unroll
        for (int l = 0; l < 8; ++l) A4[kk][l] = fmaf(f, z[l], A4[kk][l]);
        A3[kk] = fmaf(c3, zk, A3[kk]);
    }
    A2 = A2 + fmaf(p, 0.5f, uq);
    a1i += zi;
}

template<int KB>
__device__ __forceinline__ void chunk_body(const float* __restrict__ pb,
                                           float* __restrict__ o,
                                           int t0, int t1, int lane, int i, int j) {
    float A4[4][8], A3[4];
    float A2 = 0.f, a1i = 0.f;
#pragma unroll
    for (int kk = 0; kk < 4; ++kk) {
        A3[kk] = 0.f;
#pragma unroll
        for (int l = 0; l < 8; ++l) A4[kk][l] = 0.f;
    }

    float P0[8], P1[8], P2[8];
    float P0i, P0j, P1i, P1j, P2i, P2j;
    load_pt(pb, t0,     i, j, P0, P0i, P0j);
    load_pt(pb, t0 + 1, i, j, P1, P1i, P1j);
    {
        const int tc = (t0 + 2 > t1) ? t1 : t0 + 2;
        load_pt(pb, tc, i, j, P2, P2i, P2j);
    }

    const int n = t1 - t0;          // 64 or 63
    const int triples = n / 3;
    int t = t0;
    for (int r = 0; r < triples; ++r) {
        sig_step<KB>(P0, P0i, P0j, P1, P1i, P1j, A4, A3, A2, a1i);
        { const int ta = (t + 3 > t1) ? t1 : t + 3; load_pt(pb, ta, i, j, P0, P0i, P0j); }
        sig_step<KB>(P1, P1i, P1j, P2, P2i, P2j, A4, A3, A2, a1i);
        { const int tb = (t + 4 > t1) ? t1 : t + 4; load_pt(pb, tb, i, j, P1, P1i, P1j); }
        sig_step<KB>(P2, P2i, P2j, P0, P0i, P0j, A4, A3, A2, a1i);
        { const int tc = (t + 5 > t1) ? t1 : t + 5; load_pt(pb, tc, i, j, P2, P2i, P2j); }
        t += 3;
    }
    const int rem = n - triples * 3;  // 0 or 1
    if (rem >= 1) sig_step<KB>(P0, P0i, P0j, P1, P1i, P1j, A4, A3, A2, a1i);
    if (rem >= 2) sig_step<KB>(P1, P1i, P1j, P2, P2i, P2j, A4, A3, A2, a1i);

    if (KB == 0) {
        if (lane < 8) o[lane] = pb[(size_t)t1 * D8 + lane] - pb[(size_t)t0 * D8 + lane];
        o[OFF2 + lane] = A2;
    }
    *(float4*)(o + OFF3 + lane * 8 + KB) = make_float4(A3[0], A3[1], A3[2], A3[3]);
#pragma unroll
    for (int kk = 0; kk < 4; ++kk)
        store8(o + OFF4 + lane * 64 + (KB + kk) * 8, A4[kk]);
}

__global__ __launch_bounds__(128, 4) void sig_chunk_kernel(const float* __restrict__ path,
                                                           float* __restrict__ sigs) {
    const int wg   = blockIdx.x;             // b*NCHUNK + c
    const int b    = wg >> 5;
    const int c    = wg & (NCHUNK - 1);
    const int w    = threadIdx.x >> 6;
    const int lane = threadIdx.x & 63;
    const int i    = lane >> 3;
    const int j    = lane & 7;
    const int t0   = c * CSTEPS;
    const int t1   = (t0 + CSTEPS < NSTEPS) ? (t0 + CSTEPS) : NSTEPS;
    const float* __restrict__ pb = path + (size_t)b * LPATH * D8;
    float* __restrict__ o = sigs + (size_t)wg * SIGLEN;
    if (w == 0) chunk_body<0>(pb, o, t0, t1, lane, i, j);
    else        chunk_body<4>(pb, o, t0, t1, lane, i, j);
}

// ============================ Phase 2 ============================
// k-split Chen combine: 1 block (4 waves) per group; wave w owns k rows
// {2w, 2w+1} of A3/A4; A1/A2/a1i replicated. B streamed from global.

template<int NPER>
__global__ __launch_bounds__(256) void sig_combine_kernel(const float* __restrict__ in,
                                                          float* __restrict__ out) {
    const int grp  = blockIdx.x;
    const int tid  = threadIdx.x;
    const int w    = tid >> 6;               // wave id: owns k0 = 2w, 2w+1
    const int lane = tid & 63;
    const int i    = lane >> 3;
    const int j    = lane & 7;
    const int k0   = 2 * w;
    const float* __restrict__ base = in + (size_t)grp * NPER * SIGLEN;

    float A4[2][8], a3[2], A1[8], A2, a1i;
    load8(base, A1);
    a1i = base[i];
    A2  = base[OFF2 + lane];
    {
        float2 v = *(const float2*)(base + OFF3 + lane * 8 + k0);
        a3[0] = v.x; a3[1] = v.y;
    }
    load8(base + OFF4 + lane * 64 + k0 * 8,       A4[0]);
    load8(base + OFF4 + lane * 64 + (k0 + 1) * 8, A4[1]);

#pragma unroll 2
    for (int s = 1; s < NPER; ++s) {
        const float* __restrict__ B = base + (size_t)s * SIGLEN;
        // shared loads
        float B1[8];   load8(B, B1);
        const float b1i = B[i];
        const float b1j = B[j];
        const float b2t = B[OFF2 + lane];
        const float2 b1k  = *(const float2*)(B + k0);                    // B1[k]
        const float2 b3k  = *(const float2*)(B + OFF3 + lane * 8 + k0);  // B3[i,j,k]
        const float2 b2jk = *(const float2*)(B + OFF2 + j * 8 + k0);     // B2[j,k]
        // per-k loads
        float b4r[2][8], b2r[2][8], b3r[2][8];
#pragma unroll
        for (int kk = 0; kk < 2; ++kk) {
            load8(B + OFF4 + lane * 64 + (k0 + kk) * 8, b4r[kk]);  // B4[i,j,k,:]
            load8(B + OFF2 + (k0 + kk) * 8,             b2r[kk]);  // B2[k,:]
            load8(B + OFF3 + j * 64 + (k0 + kk) * 8,    b3r[kk]);  // B3[j,k,:]
        }
        // C4[i,j,k,l] = A4 + B4 + A3[k]*B1[l] + A2*B2[k,l] + A1[i]*B3[j,k,l]
#pragma unroll
        for (int kk = 0; kk < 2; ++kk) {
#pragma unroll
            for (int l = 0; l < 8; ++l) {
                float v = A4[kk][l] + b4r[kk][l];
                v = fmaf(a3[kk], B1[l], v);
                v = fmaf(A2,     b2r[kk][l], v);
                A4[kk][l] = fmaf(a1i, b3r[kk][l], v);
            }
        }
        // C3[i,j,k] = A3 + B3[i,j,k] + A2*B1[k] + A1[i]*B2[j,k]   (own k slice)
        a3[0] = fmaf(a1i, b2jk.x, fmaf(A2, b1k.x, a3[0] + b3k.x));
        a3[1] = fmaf(a1i, b2jk.y, fmaf(A2, b1k.y, a3[1] + b3k.y));
        // C2, C1
        A2 = A2 + fmaf(a1i, b1j, b2t);
#pragma unroll
        for (int m = 0; m < 8; ++m) A1[m] += B1[m];
        a1i += b1i;
    }

    float* __restrict__ o = out + (size_t)grp * SIGLEN;
    if (w == 0) {
        if (lane < 8) o[lane] = A1[lane];
        o[OFF2 + lane] = A2;
    }
    *(float2*)(o + OFF3 + lane * 8 + k0) = make_float2(a3[0], a3[1]);
    store8(o + OFF4 + lane * 64 + k0 * 8,       A4[0]);
    store8(o + OFF4 + lane * 64 + (k0 + 1) * 8, A4[1]);
}

extern "C" void kernel_launch(void* const* d_in, const int* in_sizes, int n_in,
                              void* d_out, int out_size, void* d_ws, size_t ws_size,
                              hipStream_t stream) {
    const float* path = (const float*)d_in[0];
    float* out   = (float*)d_out;
    float* sigs  = (float*)d_ws;                                  // 64*32*4680 f32 = 38.3 MB
    float* gsigs = sigs + (size_t)NBATCH * NCHUNK * SIGLEN;       // 64*4*4680 f32 = 4.8 MB

    sig_chunk_kernel<<<NBATCH * NCHUNK, 128, 0, stream>>>(path, sigs);
    sig_combine_kernel<8><<<NBATCH * 4, 256, 0, stream>>>(sigs, gsigs);
    sig_combine_kernel<4><<<NBATCH, 256, 0, stream>>>(gsigs, out);
}